// Round 9
// baseline (126.735 us; speedup 1.0000x reference)
//
#include <hip/hip_runtime.h>

#define NPSZ   16
#define NNODES 262144
#define NEDGES 1048576
#define HDIM   128

typedef float    f32x4 __attribute__((ext_vector_type(4)));
typedef _Float16 f16x8 __attribute__((ext_vector_type(8)));
typedef unsigned long long u64;

// ---- exact-erf gelu for the 31-entry degree table (accuracy-critical, tiny volume) ----
__device__ __forceinline__ float erf_fast(float x) {
    float ax = fabsf(x);
    float t  = __builtin_amdgcn_rcpf(fmaf(0.3275911f, ax, 1.0f));
    float e  = __builtin_amdgcn_exp2f(-1.44269504f * x * x);
    float p  = fmaf(1.061405429f, t, -1.453152027f);
    p = fmaf(p, t, 1.421413741f);
    p = fmaf(p, t, -0.284496736f);
    p = fmaf(p, t, 0.254829592f);
    float y = fmaf(-p * t, e, 1.0f);
    return copysignf(y, x);
}
__device__ __forceinline__ float gelu_exact(float x) {
    return 0.5f * x * (1.0f + erf_fast(0.70710678118654752f * x));
}
// ---- 7-op tanh-form gelu for the bulk epilogues (|err| <= ~1e-3 abs) ----
__device__ __forceinline__ float gelu_f(float x) {
    float x2 = x * x;
    float w  = x * fmaf(0.1029432f, x2, 2.3022081f);   // 2*log2(e)*0.7978846*(1, 0.044715)
    float e  = __builtin_amdgcn_exp2f(w);
    float r  = __builtin_amdgcn_rcpf(1.0f + e);
    return fmaf(-x, r, x);                             // x*(1 - 1/(1+2^w)) = 0.5x(1+tanh)
}
__device__ __forceinline__ unsigned short f16bits(float v) {
    union { _Float16 h; unsigned short u; } c;
    c.h = (_Float16)v;
    return c.u;
}
__device__ __forceinline__ unsigned pkrtz(float a, float b) {
    return __builtin_bit_cast(unsigned, __builtin_amdgcn_cvt_pkrtz(a, b));
}

// ================= k_edges: nibble histograms, 8-way split to cut atomic conflicts =================
__global__ __launch_bounds__(256) void k_edges(const int* __restrict__ ei,
                                               u64* __restrict__ hist8) {
    const int blk = blockIdx.x;
    u64* __restrict__ h = hist8 + (size_t)(blk & 7) * NNODES;
    const int e4 = (blk * 256 + threadIdx.x) * 4;
    const int4 s4 = *(const int4*)(ei + e4);
    const int4 d4 = *(const int4*)(ei + NEDGES + e4);
    atomicAdd(h + d4.x, 1ull << ((s4.x & 15) * 4));
    atomicAdd(h + d4.y, 1ull << ((s4.y & 15) * 4));
    atomicAdd(h + d4.z, 1ull << ((s4.z & 15) * 4));
    atomicAdd(h + d4.w, 1ull << ((s4.w & 15) * 4));
}

// ================= k_tab: degree table rows 0..30 | b2a row 31 | weight frag images =================
// taf[(n*64 + (d>>3)*16 + r)*8 + (d&7)] = f16(TA[d][16n+r]);  row 31 = b2a (agg-MFMA bias fold)
__global__ __launch_bounds__(256) void k_tab(
    const float* __restrict__ W1a, const float* __restrict__ b1a,
    const float* __restrict__ W1b, const float* __restrict__ b1b,
    const float* __restrict__ W2a, const float* __restrict__ b2a,
    const float* __restrict__ W2b, const float* __restrict__ Wf0,
    unsigned short* __restrict__ taf,
    unsigned short* __restrict__ w1f, unsigned short* __restrict__ w2f) {
    __shared__ float t1[HDIM];
    __shared__ float t2[HDIM];
    const int blk = blockIdx.x, t = threadIdx.x;
    if (blk < 31) {
        const int d = blk;
        if (t < HDIM) t1[t] = gelu_exact((1.0f + (float)d) * W1a[t] + b1a[t]);
        __syncthreads();
        if (t < HDIM) {
            float a = b1b[t];
            for (int k = 0; k < HDIM; ++k) a = fmaf(t1[k], W1b[k * HDIM + t], a);
            t2[t] = gelu_exact(a);
        }
        __syncthreads();
        if (t < HDIM) {
            float a = 0.f;
            for (int k = 0; k < HDIM; ++k) a = fmaf(t2[k], W2a[k * HDIM + t], a);
            const int n = t >> 4, r = t & 15;
            taf[(size_t)(n * 64 + (d >> 3) * 16 + r) * 8 + (d & 7)] = f16bits(a);
        }
    } else if (blk == 31) {
        if (t < HDIM) {
            const int n = t >> 4, r = t & 15;
            taf[(size_t)(n * 64 + 3 * 16 + r) * 8 + 7] = f16bits(b2a[t]);
        }
    } else {
        const int id = (blk - 32) * 256 + t;     // 0..4095
        const int sel = id >> 11;
        const int f = id & 2047;                 // ks*512 + n*64 + l
        const int ks = f >> 9, n = (f >> 6) & 7, l = f & 63;
        const int r = l & 15, h = l >> 4;
        const float* W = sel ? Wf0 : W2b;
        union { unsigned short u[8]; f32x4 v; } pk;
        #pragma unroll
        for (int jj = 0; jj < 8; ++jj)
            pk.u[jj] = f16bits(W[(32 * ks + 8 * h + jj) * HDIM + 16 * n + r]);
        *(f32x4*)((sel ? w2f : w1f) + f * 8) = pk.v;
    }
}

// ================= k_fused: agg(MFMA) -> GEMM1 -> GEMM2 -> pool -> fc1 =================
// 512 thr (8 waves), wave owns 16 rows = 1 subgraph. LDS = 32 KB hbuf only, 0 barriers.
#define LOAD8(DST, IMG, KS)                                                        \
    {                                                                              \
        _Pragma("unroll")                                                          \
        for (int n = 0; n < 8; ++n)                                                \
            DST[n] = *(const f16x8*)((IMG) + ((KS) * 8 + n) * 64 + ln);            \
    }
#define MFMA8(ACC, A, B)                                                           \
    {                                                                              \
        _Pragma("unroll")                                                          \
        for (int n = 0; n < 8; ++n)                                                \
            ACC[n] = __builtin_amdgcn_mfma_f32_16x16x32_f16(A, B[n], ACC[n], 0, 0, 0); \
    }
#define AFRAG(KS) (*(const f16x8*)(myb + i * 256 + ((((4 * (KS) + g)) ^ i) << 4)))
// store MFMA-C-layout value (row=4g+j, col=16n+i) into A-layout swizzled hbuf
#define CSTORE(VAL, N, J)                                                          \
    {                                                                              \
        const int row_ = 4 * g + (J);                                              \
        const int slot_ = (2 * (N) + (i >> 3)) ^ row_;                             \
        *(unsigned short*)(myb + row_ * 256 + (slot_ << 4) + ((i & 7) << 1)) = f16bits(VAL); \
    }

__global__ __launch_bounds__(512, 4) void k_fused(
    const u64* __restrict__ hist8,
    const f32x4* __restrict__ taf,
    const f32x4* __restrict__ w1f, const f32x4* __restrict__ w2f,
    const float* __restrict__ b2b,
    const float* __restrict__ bf0, const float* __restrict__ wf1,
    const float* __restrict__ bf1, float* __restrict__ res) {
    __shared__ char hbuf[32768];   // 4 KB per wave, 16 rows x 256B, chunk-XOR row

    const int t = threadIdx.x, blk = blockIdx.x;
    const int ln = t & 63, wv = t >> 6;
    const int i = ln & 15, g = ln >> 4;
    char* const myb = hbuf + (wv << 12);

    // TA B-frags (L2-hot, 8 x 16B per lane)
    f16x8 tf[8];
    LOAD8(tf, taf, 0)

    // ---- summed histogram for this node ----
    const int node = blk * 128 + wv * 16 + i;
    u64 hv = 0;
    #pragma unroll
    for (int c = 0; c < 8; ++c) hv += hist8[(size_t)c * NNODES + node];

    // ---- degree (clamped to 30; row 31 is the b2a bias row) ----
    int dv;
    {
        u64 x = (hv & 0x0F0F0F0F0F0F0F0Full) + ((hv >> 4) & 0x0F0F0F0F0F0F0F0Full);
        x += x >> 32; x += x >> 16; x += x >> 8;
        dv = (int)(x & 0xFF);
        dv = dv < 30 ? dv : 30;
    }
    // ---- degpack: all 16 clamped degrees of this subgraph, 8-bit lanes ----
    u64 p0 = (i < 8) ? ((u64)dv << (8 * i)) : 0;
    u64 p1 = (i >= 8) ? ((u64)dv << (8 * (i - 8))) : 0;
    #pragma unroll
    for (int m = 1; m <= 8; m <<= 1) {
        p0 |= __shfl_xor(p0, m, 64);
        p1 |= __shfl_xor(p1, m, 64);
    }

    // ---- build M row (node i): two u64 nibble-packs over degree-index 0..31 ----
    u64 m0 = 0, m1 = 1ull << 60;   // slot 31 = +1 * b2a row (bias fold)
    {   // self term: M[i][dv] += 1
        const u64 inc = 1ull << (4 * (dv & 15));
        if (dv < 16) m0 = inc; else m1 += inc;
    }
    {
        u64 h = hv;
        while (h) {
            const int b = __builtin_ctzll(h) & ~3;
            const int slot = b >> 2;
            const u64 c = (h >> b) & 15ull;
            h &= ~(15ull << b);
            const int ds = (int)(((slot < 8 ? p0 : p1) >> (8 * (slot & 7))) & 31ull);
            const u64 inc = c << (4 * (ds & 15));
            if (ds < 16) m0 += inc; else m1 += inc;
        }
    }
    // ---- expand this lane's 8 k-slots (k = 8g..8g+7) to f16 A-frag ----
    f16x8 afr;
    {
        const u64 half = (g & 2) ? m1 : m0;
        const unsigned q = (g & 1) ? (unsigned)(half >> 32) : (unsigned)half;
        union { unsigned w[4]; f16x8 v; } mu;
        #pragma unroll
        for (int j = 0; j < 4; ++j)
            mu.w[j] = pkrtz((float)((q >> (8 * j)) & 15u), (float)((q >> (8 * j + 4)) & 15u));
        afr = mu.v;
    }

    // ---- agg MFMA: acc = M @ TA (b2a folded via row 31) ----
    f32x4 acc[8];
    #pragma unroll
    for (int n = 0; n < 8; ++n) acc[n] = (f32x4){0.f, 0.f, 0.f, 0.f};
    MFMA8(acc, afr, tf)

    // prefetch GEMM1 slice-0 B-frags (latency hidden under epilogue0 gelu)
    f16x8 bfA[8], bfB[8];
    LOAD8(bfA, w1f, 0)

    // ---- epilogue0: h2a = gelu(acc) -> hbuf (A-layout) ----
    #pragma unroll
    for (int n = 0; n < 8; ++n) {
        #pragma unroll
        for (int j = 0; j < 4; ++j)
            CSTORE(gelu_f(acc[n][j]), n, j)
    }

    // ---- GEMM1: acc = h2a @ W2b (B-frags streamed from global, ping-pong) ----
    #pragma unroll
    for (int n = 0; n < 8; ++n) acc[n] = (f32x4){0.f, 0.f, 0.f, 0.f};
    {
        LOAD8(bfB, w1f, 1)
        { const f16x8 a = AFRAG(0); MFMA8(acc, a, bfA) }
        LOAD8(bfA, w1f, 2)
        { const f16x8 a = AFRAG(1); MFMA8(acc, a, bfB) }
        LOAD8(bfB, w1f, 3)
        { const f16x8 a = AFRAG(2); MFMA8(acc, a, bfA) }
        LOAD8(bfA, w2f, 0)   // prefetch GEMM2 slice 0
        { const f16x8 a = AFRAG(3); MFMA8(acc, a, bfB) }
    }

    // ---- epilogue1: h2b = gelu(acc + b2b) -> hbuf ----
    #pragma unroll
    for (int n = 0; n < 8; ++n) {
        const float bb = b2b[16 * n + i];
        #pragma unroll
        for (int j = 0; j < 4; ++j)
            CSTORE(gelu_f(acc[n][j] + bb), n, j)
    }

    // ---- GEMM2: acc2 = h2b @ Wf0 ----
    f32x4 acc2[8];
    #pragma unroll
    for (int n = 0; n < 8; ++n) acc2[n] = (f32x4){0.f, 0.f, 0.f, 0.f};
    {
        LOAD8(bfB, w2f, 1)
        { const f16x8 a = AFRAG(0); MFMA8(acc2, a, bfA) }
        LOAD8(bfA, w2f, 2)
        { const f16x8 a = AFRAG(1); MFMA8(acc2, a, bfB) }
        LOAD8(bfB, w2f, 3)
        { const f16x8 a = AFRAG(2); MFMA8(acc2, a, bfA) }
        { const f16x8 a = AFRAG(3); MFMA8(acc2, a, bfB) }
    }

    // ---- epilogue2: h3 = gelu(acc2 + bf0); pool 16 rows; dot wf1 ----
    float p = 0.f;
    #pragma unroll
    for (int n = 0; n < 8; ++n) {
        const float bb = bf0[16 * n + i];
        const float ww = wf1[16 * n + i];
        #pragma unroll
        for (int j = 0; j < 4; ++j)
            p = fmaf(gelu_f(acc2[n][j] + bb), ww, p);
    }
    #pragma unroll
    for (int off = 32; off; off >>= 1) p += __shfl_xor(p, off, 64);
    if (ln == 0) res[blk * 8 + wv] = p + bf1[0];
}

extern "C" void kernel_launch(void* const* d_in, const int* in_sizes, int n_in,
                              void* d_out, int out_size, void* d_ws, size_t ws_size,
                              hipStream_t stream) {
    const int*   ei  = (const int*)d_in[0];
    const float* W1a = (const float*)d_in[4];
    const float* b1a = (const float*)d_in[5];
    const float* W1b = (const float*)d_in[6];
    const float* b1b = (const float*)d_in[7];
    const float* W2a = (const float*)d_in[8];
    const float* b2a = (const float*)d_in[9];
    const float* W2b = (const float*)d_in[10];
    const float* b2b = (const float*)d_in[11];
    const float* Wf0 = (const float*)d_in[12];
    const float* bf0 = (const float*)d_in[13];
    const float* Wf1 = (const float*)d_in[14];
    const float* bf1 = (const float*)d_in[15];

    char* ws = (char*)d_ws;
    u64* hist8          = (u64*)ws;                                         // 16 MB
    unsigned short* taf = (unsigned short*)(ws + (16 << 20));               // 8 KB
    unsigned short* w1f = (unsigned short*)(ws + (16 << 20) + 8192);        // 32 KB
    unsigned short* w2f = (unsigned short*)(ws + (16 << 20) + 8192 + 32768);// 32 KB
    float* res          = (float*)d_out;

    (void)hipMemsetAsync(hist8, 0, (size_t)8 * NNODES * sizeof(u64), stream);
    hipLaunchKernelGGL(k_edges, dim3(1024), dim3(256), 0, stream, ei, hist8);
    hipLaunchKernelGGL(k_tab, dim3(48), dim3(256), 0, stream,
                       W1a, b1a, W1b, b1b, W2a, b2a, W2b, Wf0, taf, w1f, w2f);
    hipLaunchKernelGGL(k_fused, dim3(2048), dim3(512), 0, stream,
                       hist8, (const f32x4*)taf,
                       (const f32x4*)w1f, (const f32x4*)w2f,
                       b2b, bf0, Wf1, bf1, res);
}

// Round 10
// 111.205 us; speedup vs baseline: 1.1397x; 1.1397x over previous
//
#include <hip/hip_runtime.h>

#define NPSZ   16
#define NNODES 262144
#define NEDGES 1048576
#define HDIM   128

typedef float    f32x4 __attribute__((ext_vector_type(4)));
typedef _Float16 f16x8 __attribute__((ext_vector_type(8)));
typedef unsigned long long u64;

// ---- exact-erf gelu for the 31-entry degree table (accuracy-critical, tiny volume) ----
__device__ __forceinline__ float erf_fast(float x) {
    float ax = fabsf(x);
    float t  = __builtin_amdgcn_rcpf(fmaf(0.3275911f, ax, 1.0f));
    float e  = __builtin_amdgcn_exp2f(-1.44269504f * x * x);
    float p  = fmaf(1.061405429f, t, -1.453152027f);
    p = fmaf(p, t, 1.421413741f);
    p = fmaf(p, t, -0.284496736f);
    p = fmaf(p, t, 0.254829592f);
    float y = fmaf(-p * t, e, 1.0f);
    return copysignf(y, x);
}
__device__ __forceinline__ float gelu_exact(float x) {
    return 0.5f * x * (1.0f + erf_fast(0.70710678118654752f * x));
}
// ---- 7-op tanh-form gelu for the bulk epilogues (|err| <= ~1e-3 abs) ----
__device__ __forceinline__ float gelu_f(float x) {
    float x2 = x * x;
    float w  = x * fmaf(0.1029432f, x2, 2.3022081f);   // 2*log2(e)*0.7978846*(1, 0.044715)
    float e  = __builtin_amdgcn_exp2f(w);
    float r  = __builtin_amdgcn_rcpf(1.0f + e);
    return fmaf(-x, r, x);                             // x*(1 - 1/(1+2^w)) = 0.5x(1+tanh)
}
__device__ __forceinline__ unsigned short f16bits(float v) {
    union { _Float16 h; unsigned short u; } c;
    c.h = (_Float16)v;
    return c.u;
}
__device__ __forceinline__ unsigned pkrtz(float a, float b) {
    return __builtin_bit_cast(unsigned, __builtin_amdgcn_cvt_pkrtz(a, b));
}

// ================= k_pre =================
// blk <1024 : edge pass -> single nibble histogram hist[d] (16 x 4-bit src-slot counts)
// 1024..1054: degree-table row d=blk-1024 (0..30) -> taf B-frag image
//             taf[(n*64 + (d>>3)*16 + r)*8 + (d&7)] = f16(TA[d][16n+r])
// 1055      : b2a into table row 31 (bias folded into agg MFMA)
// 1056..1071: weight B-frag images w1f/w2f: frag[ks][n][lane][jj] = W[32ks+8(l>>4)+jj][16n+(l&15)]
__global__ __launch_bounds__(256) void k_pre(
    const int* __restrict__ ei, u64* __restrict__ hist,
    const float* __restrict__ W1a, const float* __restrict__ b1a,
    const float* __restrict__ W1b, const float* __restrict__ b1b,
    const float* __restrict__ W2a, const float* __restrict__ b2a,
    const float* __restrict__ W2b, const float* __restrict__ Wf0,
    unsigned short* __restrict__ taf,
    unsigned short* __restrict__ w1f, unsigned short* __restrict__ w2f) {
    __shared__ float t1[HDIM];
    __shared__ float t2[HDIM];
    const int blk = blockIdx.x, t = threadIdx.x;
    if (blk < 1024) {
        const int e4 = (blk * 256 + t) * 4;
        const int4 s4 = *(const int4*)(ei + e4);
        const int4 d4 = *(const int4*)(ei + NEDGES + e4);
        atomicAdd(hist + d4.x, 1ull << ((s4.x & 15) * 4));
        atomicAdd(hist + d4.y, 1ull << ((s4.y & 15) * 4));
        atomicAdd(hist + d4.z, 1ull << ((s4.z & 15) * 4));
        atomicAdd(hist + d4.w, 1ull << ((s4.w & 15) * 4));
    } else if (blk < 1055) {
        const int d = blk - 1024;
        if (t < HDIM) t1[t] = gelu_exact((1.0f + (float)d) * W1a[t] + b1a[t]);
        __syncthreads();
        if (t < HDIM) {
            float a = b1b[t];
            for (int k = 0; k < HDIM; ++k) a = fmaf(t1[k], W1b[k * HDIM + t], a);
            t2[t] = gelu_exact(a);
        }
        __syncthreads();
        if (t < HDIM) {
            float a = 0.f;
            for (int k = 0; k < HDIM; ++k) a = fmaf(t2[k], W2a[k * HDIM + t], a);
            const int n = t >> 4, r = t & 15;
            taf[(size_t)(n * 64 + (d >> 3) * 16 + r) * 8 + (d & 7)] = f16bits(a);
        }
    } else if (blk == 1055) {
        if (t < HDIM) {
            const int n = t >> 4, r = t & 15;
            taf[(size_t)(n * 64 + 3 * 16 + r) * 8 + 7] = f16bits(b2a[t]);
        }
    } else {
        const int id = (blk - 1056) * 256 + t;   // 0..4095
        const int sel = id >> 11;
        const int f = id & 2047;                 // ks*512 + n*64 + l
        const int ks = f >> 9, n = (f >> 6) & 7, l = f & 63;
        const int r = l & 15, h = l >> 4;
        const float* W = sel ? Wf0 : W2b;
        union { unsigned short u[8]; f32x4 v; } pk;
        #pragma unroll
        for (int jj = 0; jj < 8; ++jj)
            pk.u[jj] = f16bits(W[(32 * ks + 8 * h + jj) * HDIM + 16 * n + r]);
        *(f32x4*)((sel ? w2f : w1f) + f * 8) = pk.v;
    }
}

// ================= k_fused: agg(MFMA) -> GEMM1 -> GEMM2 -> pool -> fc1 =================
// 512 thr (8 waves), wave owns 16 rows = 1 subgraph. LDS = 32 KB hbuf only, 0 barriers.
#define LOAD8(DST, IMG, KS)                                                        \
    {                                                                              \
        _Pragma("unroll")                                                          \
        for (int n = 0; n < 8; ++n)                                                \
            DST[n] = *(const f16x8*)((IMG) + ((KS) * 8 + n) * 64 + ln);            \
    }
#define MFMA8(ACC, A, B)                                                           \
    {                                                                              \
        _Pragma("unroll")                                                          \
        for (int n = 0; n < 8; ++n)                                                \
            ACC[n] = __builtin_amdgcn_mfma_f32_16x16x32_f16(A, B[n], ACC[n], 0, 0, 0); \
    }
#define AFRAG(KS) (*(const f16x8*)(myb + i * 256 + ((((4 * (KS) + g)) ^ i) << 4)))
// store MFMA-C-layout value (row=4g+j, col=16n+i) into A-layout swizzled hbuf
#define CSTORE(VAL, N, J)                                                          \
    {                                                                              \
        const int row_ = 4 * g + (J);                                              \
        const int slot_ = (2 * (N) + (i >> 3)) ^ row_;                             \
        *(unsigned short*)(myb + row_ * 256 + (slot_ << 4) + ((i & 7) << 1)) = f16bits(VAL); \
    }

__global__ __launch_bounds__(512, 4) void k_fused(
    const u64* __restrict__ hist,
    const f32x4* __restrict__ taf,
    const f32x4* __restrict__ w1f, const f32x4* __restrict__ w2f,
    const float* __restrict__ b2b,
    const float* __restrict__ bf0, const float* __restrict__ wf1,
    const float* __restrict__ bf1, float* __restrict__ res) {
    __shared__ char hbuf[32768];   // 4 KB per wave, 16 rows x 256B, chunk-XOR row

    const int t = threadIdx.x, blk = blockIdx.x;
    const int ln = t & 63, wv = t >> 6;
    const int i = ln & 15, g = ln >> 4;
    char* const myb = hbuf + (wv << 12);

    // TA B-frags (L2-hot, 8 x 16B per lane)
    f16x8 tf[8];
    LOAD8(tf, taf, 0)

    // ---- histogram for this node ----
    const int node = blk * 128 + wv * 16 + i;
    const u64 hv = hist[node];

    // ---- degree (clamped to 30; row 31 is the b2a bias row) ----
    int dv;
    {
        u64 x = (hv & 0x0F0F0F0F0F0F0F0Full) + ((hv >> 4) & 0x0F0F0F0F0F0F0F0Full);
        x += x >> 32; x += x >> 16; x += x >> 8;
        dv = (int)(x & 0xFF);
        dv = dv < 30 ? dv : 30;
    }
    // ---- degpack: all 16 clamped degrees of this subgraph, 8-bit lanes ----
    u64 p0 = (i < 8) ? ((u64)dv << (8 * i)) : 0;
    u64 p1 = (i >= 8) ? ((u64)dv << (8 * (i - 8))) : 0;
    #pragma unroll
    for (int m = 1; m <= 8; m <<= 1) {
        p0 |= __shfl_xor(p0, m, 64);
        p1 |= __shfl_xor(p1, m, 64);
    }

    // ---- build M row (node i): two u64 nibble-packs over degree-index 0..31 ----
    u64 m0 = 0, m1 = 1ull << 60;   // slot 31 = +1 * b2a row (bias fold)
    {   // self term: M[i][dv] += 1
        const u64 inc = 1ull << (4 * (dv & 15));
        if (dv < 16) m0 = inc; else m1 += inc;
    }
    {
        u64 h = hv;
        while (h) {
            const int b = __builtin_ctzll(h) & ~3;
            const int slot = b >> 2;
            const u64 c = (h >> b) & 15ull;
            h &= ~(15ull << b);
            const int ds = (int)(((slot < 8 ? p0 : p1) >> (8 * (slot & 7))) & 31ull);
            const u64 inc = c << (4 * (ds & 15));
            if (ds < 16) m0 += inc; else m1 += inc;
        }
    }
    // ---- expand this lane's 8 k-slots (k = 8g..8g+7) to f16 A-frag ----
    f16x8 afr;
    {
        const u64 half = (g & 2) ? m1 : m0;
        const unsigned q = (g & 1) ? (unsigned)(half >> 32) : (unsigned)half;
        union { unsigned w[4]; f16x8 v; } mu;
        #pragma unroll
        for (int j = 0; j < 4; ++j)
            mu.w[j] = pkrtz((float)((q >> (8 * j)) & 15u), (float)((q >> (8 * j + 4)) & 15u));
        afr = mu.v;
    }

    // ---- agg MFMA: acc = M @ TA (b2a folded via row 31) ----
    f32x4 acc[8];
    #pragma unroll
    for (int n = 0; n < 8; ++n) acc[n] = (f32x4){0.f, 0.f, 0.f, 0.f};
    MFMA8(acc, afr, tf)

    // prefetch GEMM1 slice-0 B-frags (latency hidden under epilogue0 gelu)
    f16x8 bfA[8], bfB[8];
    LOAD8(bfA, w1f, 0)

    // ---- epilogue0: h2a = gelu(acc) -> hbuf (A-layout) ----
    #pragma unroll
    for (int n = 0; n < 8; ++n) {
        #pragma unroll
        for (int j = 0; j < 4; ++j)
            CSTORE(gelu_f(acc[n][j]), n, j)
    }

    // ---- GEMM1: acc = h2a @ W2b (B-frags streamed from global, ping-pong) ----
    #pragma unroll
    for (int n = 0; n < 8; ++n) acc[n] = (f32x4){0.f, 0.f, 0.f, 0.f};
    {
        LOAD8(bfB, w1f, 1)
        { const f16x8 a = AFRAG(0); MFMA8(acc, a, bfA) }
        LOAD8(bfA, w1f, 2)
        { const f16x8 a = AFRAG(1); MFMA8(acc, a, bfB) }
        LOAD8(bfB, w1f, 3)
        { const f16x8 a = AFRAG(2); MFMA8(acc, a, bfA) }
        LOAD8(bfA, w2f, 0)   // prefetch GEMM2 slice 0
        { const f16x8 a = AFRAG(3); MFMA8(acc, a, bfB) }
    }

    // ---- epilogue1: h2b = gelu(acc + b2b) -> hbuf ----
    #pragma unroll
    for (int n = 0; n < 8; ++n) {
        const float bb = b2b[16 * n + i];
        #pragma unroll
        for (int j = 0; j < 4; ++j)
            CSTORE(gelu_f(acc[n][j] + bb), n, j)
    }

    // ---- GEMM2: acc2 = h2b @ Wf0 ----
    f32x4 acc2[8];
    #pragma unroll
    for (int n = 0; n < 8; ++n) acc2[n] = (f32x4){0.f, 0.f, 0.f, 0.f};
    {
        LOAD8(bfB, w2f, 1)
        { const f16x8 a = AFRAG(0); MFMA8(acc2, a, bfA) }
        LOAD8(bfA, w2f, 2)
        { const f16x8 a = AFRAG(1); MFMA8(acc2, a, bfB) }
        LOAD8(bfB, w2f, 3)
        { const f16x8 a = AFRAG(2); MFMA8(acc2, a, bfA) }
        { const f16x8 a = AFRAG(3); MFMA8(acc2, a, bfB) }
    }

    // ---- epilogue2: h3 = gelu(acc2 + bf0); pool 16 rows; dot wf1 ----
    float p = 0.f;
    #pragma unroll
    for (int n = 0; n < 8; ++n) {
        const float bb = bf0[16 * n + i];
        const float ww = wf1[16 * n + i];
        #pragma unroll
        for (int j = 0; j < 4; ++j)
            p = fmaf(gelu_f(acc2[n][j] + bb), ww, p);
    }
    #pragma unroll
    for (int off = 32; off; off >>= 1) p += __shfl_xor(p, off, 64);
    if (ln == 0) res[blk * 8 + wv] = p + bf1[0];
}

extern "C" void kernel_launch(void* const* d_in, const int* in_sizes, int n_in,
                              void* d_out, int out_size, void* d_ws, size_t ws_size,
                              hipStream_t stream) {
    const int*   ei  = (const int*)d_in[0];
    const float* W1a = (const float*)d_in[4];
    const float* b1a = (const float*)d_in[5];
    const float* W1b = (const float*)d_in[6];
    const float* b1b = (const float*)d_in[7];
    const float* W2a = (const float*)d_in[8];
    const float* b2a = (const float*)d_in[9];
    const float* W2b = (const float*)d_in[10];
    const float* b2b = (const float*)d_in[11];
    const float* Wf0 = (const float*)d_in[12];
    const float* bf0 = (const float*)d_in[13];
    const float* Wf1 = (const float*)d_in[14];
    const float* bf1 = (const float*)d_in[15];

    char* ws = (char*)d_ws;
    u64* hist           = (u64*)ws;                                        // 2 MB
    unsigned short* taf = (unsigned short*)(ws + (2 << 20));               // 8 KB
    unsigned short* w1f = (unsigned short*)(ws + (2 << 20) + 8192);        // 32 KB
    unsigned short* w2f = (unsigned short*)(ws + (2 << 20) + 8192 + 32768);// 32 KB
    float* res          = (float*)d_out;

    (void)hipMemsetAsync(hist, 0, NNODES * sizeof(u64), stream);
    hipLaunchKernelGGL(k_pre, dim3(1072), dim3(256), 0, stream,
                       ei, hist, W1a, b1a, W1b, b1b, W2a, b2a, W2b, Wf0,
                       taf, w1f, w2f);
    hipLaunchKernelGGL(k_fused, dim3(2048), dim3(512), 0, stream,
                       hist, (const f32x4*)taf,
                       (const f32x4*)w1f, (const f32x4*)w2f,
                       b2b, bf0, Wf1, bf1, res);
}